// Round 8
// baseline (205.536 us; speedup 1.0000x reference)
//
#include <hip/hip_runtime.h>
#include <hip/hip_bf16.h>

using bf16 = __hip_bfloat16;
typedef short bf16x8 __attribute__((ext_vector_type(8)));
typedef float f32x4 __attribute__((ext_vector_type(4)));
typedef float f32x16 __attribute__((ext_vector_type(16)));
typedef unsigned short ushort8_t __attribute__((ext_vector_type(8)));
typedef unsigned long long u64;

static constexpr int NA_ = 2048, NB_ = 2048;
static constexpr int H_ = 8, DH_ = 64, INNER_ = 512;
static constexpr int MROWS = 2 * NA_;  // 4096 rows for both batches

#define MFMA32(a, b, c) __builtin_amdgcn_mfma_f32_16x16x32_bf16(a, b, c, 0, 0, 0)
#define MFMA3216(a, b, c) __builtin_amdgcn_mfma_f32_32x32x16_bf16(a, b, c, 0, 0, 0)

__device__ __forceinline__ unsigned short bfbits(float x) {
  bf16 h = __float2bfloat16(x);
  return __builtin_bit_cast(unsigned short, h);
}
__device__ __forceinline__ float b2f(unsigned short u) {
  unsigned v = ((unsigned)u) << 16;
  return __builtin_bit_cast(float, v);
}

// ======== prep: ln_feat (blocks 0..2047) | wconv (2048..4607) | maskpack (4608..6655)
__global__ __launch_bounds__(256) void prep_kernel(
    const float* __restrict__ fa_in, const float* __restrict__ fb_in,
    const float* __restrict__ law, const float* __restrict__ lab,
    const float* __restrict__ lbw, const float* __restrict__ lbb,
    bf16* __restrict__ fa, bf16* __restrict__ fb,
    const float* __restrict__ Wq, const float* __restrict__ Wk,
    const float* __restrict__ Wv, const float* __restrict__ Wg,
    const float* __restrict__ Wo,
    bf16* __restrict__ Wqt, bf16* __restrict__ Wkt,
    bf16* __restrict__ Wvt, bf16* __restrict__ Wgt,
    bf16* __restrict__ Woth, bf16* __restrict__ Wotl,
    const void* __restrict__ maskp, u64* __restrict__ mbits) {
  int blk = blockIdx.x;
  int t = threadIdx.x;
  if (blk < 2048) {
    int row = blk * 4 + (t >> 6);
    int lane = t & 63;
    const float *src, *w, *bb;
    bf16* dst;
    int r;
    if (row < MROWS) { src = fa_in; w = law; bb = lab; dst = fa; r = row; }
    else             { src = fb_in; w = lbw; bb = lbb; dst = fb; r = row - MROWS; }
    float4 x = *(const float4*)(src + (size_t)r * 256 + lane * 4);
    float s  = (x.x + x.y) + (x.z + x.w);
    float s2 = (x.x * x.x + x.y * x.y) + (x.z * x.z + x.w * x.w);
#pragma unroll
    for (int m = 32; m >= 1; m >>= 1) { s += __shfl_xor(s, m); s2 += __shfl_xor(s2, m); }
    float mean = s * (1.0f / 256.0f);
    float var  = s2 * (1.0f / 256.0f) - mean * mean;
    float rstd = rsqrtf(var + 1e-5f);
    float4 wv = *(const float4*)(w + lane * 4);
    float4 bv = *(const float4*)(bb + lane * 4);
    ushort4 o;
    o.x = bfbits((x.x - mean) * rstd * wv.x + bv.x);
    o.y = bfbits((x.y - mean) * rstd * wv.y + bv.y);
    o.z = bfbits((x.z - mean) * rstd * wv.z + bv.z);
    o.w = bfbits((x.w - mean) * rstd * wv.w + bv.w);
    *(ushort4*)(dst + (size_t)r * 256 + lane * 4) = o;
  } else if (blk < 4608) {
    int z = (blk - 2048) >> 9;
    int idx = ((blk - 2048) & 511) * 256 + t;
    if (z < 4) {
      const float* W = (z == 0) ? Wq : (z == 1) ? Wk : (z == 2) ? Wv : Wg;
      bf16* Wt = (z == 0) ? Wqt : (z == 1) ? Wkt : (z == 2) ? Wvt : Wgt;
      int kk = idx >> 9, n = idx & 511;
      Wt[n * 256 + kk] = __float2bfloat16(W[idx]);
    } else {
      int kk = idx >> 8, n = idx & 255;
      float w = Wo[idx];
      bf16 hi = __float2bfloat16(w);
      Woth[n * 512 + kk] = hi;
      Wotl[n * 512 + kk] = __float2bfloat16(w - __bfloat162float(hi));
    }
  } else {
    __shared__ unsigned shf[4];
    const unsigned char* mu = (const unsigned char*)maskp;
    bool nz = ((t & 3) != 0) && (mu[t] != 0);
    u64 bal = __ballot(nz);
    if ((t & 63) == 0) shf[t >> 6] = (bal != 0ull) ? 1u : 0u;
    __syncthreads();
    bool m8 = (shf[0] | shf[1] | shf[2] | shf[3]) != 0;
    int lane = t & 63, wid = t >> 6;
    int lb = blk - 4608;
    for (size_t word = (size_t)lb * 4 + wid; word < 131072; word += 8192) {
      size_t e = word * 64 + lane;
      int v = m8 ? (int)mu[e] : ((const int*)maskp)[e];
      u64 b2 = __ballot(v != 0);
      if (lane == 0) mbits[word] = b2;
    }
  }
}

// ======== all four pre-GEMMs in one launch: grid dim3(256,1,4) (unchanged R5/R7) ====
__global__ __launch_bounds__(256) void gemm4_kernel(
    const bf16* __restrict__ fa, const bf16* __restrict__ fb,
    const bf16* __restrict__ Wqt, const bf16* __restrict__ Wkt,
    const bf16* __restrict__ Wgt, const bf16* __restrict__ Wvt,
    const float* __restrict__ bq, const float* __restrict__ bk,
    const float* __restrict__ bg, const float* __restrict__ bv,
    const float* __restrict__ qlw, const float* __restrict__ qlb,
    const float* __restrict__ klw, const float* __restrict__ klb,
    bf16* __restrict__ qo, bf16* __restrict__ ko,
    bf16* __restrict__ gout, bf16* __restrict__ vout) {
  __shared__ __align__(16) char sm[27648];
  int z = blockIdx.z;
  int t = threadIdx.x, wave = t >> 6, lane = t & 63;
  int lm = lane & 15, quad = lane >> 4, q8 = quad * 8;

  if (z < 2) {
    bf16* As = (bf16*)sm;
    float* Pred = (float*)(sm + 16896);
    float* MV   = (float*)(sm + 17408);
    const bf16* A    = z ? fb : fa;
    const bf16* Wt   = z ? Wkt : Wqt;
    const float* bias = z ? bk : bq;
    const float* lw  = z ? klw : qlw;
    const float* lb  = z ? klb : qlb;
    bf16* out        = z ? ko : qo;
    int m0 = blockIdx.x * 16;
#pragma unroll
    for (int i = 0; i < 2; i++) {
      int id = t + 256 * i, r = id >> 5, cg = id & 31;
      *(ushort8_t*)(&As[r * 264 + cg * 8]) =
          *(const ushort8_t*)(A + (size_t)(m0 + r) * 256 + cg * 8);
    }
    __syncthreads();
    int n0w = wave * 128;
    f32x4 acc[8] = {};
    const bf16* wrow[8];
#pragma unroll
    for (int ni = 0; ni < 8; ni++) wrow[ni] = Wt + (size_t)(n0w + ni * 16 + lm) * 256;
#pragma unroll
    for (int ks = 0; ks < 8; ks++) {
      int k0 = ks * 32;
      bf16x8 af = *(const bf16x8*)(&As[lm * 264 + k0 + q8]);
#pragma unroll
      for (int ni = 0; ni < 8; ni++) {
        bf16x8 bf_ = *(const bf16x8*)(wrow[ni] + k0 + q8);
        acc[ni] = MFMA32(af, bf_, acc[ni]);
      }
    }
    float bvv[8];
#pragma unroll
    for (int ni = 0; ni < 8; ni++) bvv[ni] = bias[n0w + ni * 16 + lm];
#pragma unroll
    for (int ni = 0; ni < 8; ni++)
#pragma unroll
      for (int r = 0; r < 4; r++) acc[ni][r] += bvv[ni];
#pragma unroll
    for (int r = 0; r < 4; r++) {
      float s = 0.f, s2 = 0.f;
#pragma unroll
      for (int ni = 0; ni < 8; ni++) { s += acc[ni][r]; s2 += acc[ni][r] * acc[ni][r]; }
#pragma unroll
      for (int m = 1; m <= 8; m <<= 1) { s += __shfl_xor(s, m); s2 += __shfl_xor(s2, m); }
      if (lm == 0) {
        int row = quad * 4 + r;
        Pred[row * 8 + wave * 2]     = s;
        Pred[row * 8 + wave * 2 + 1] = s2;
      }
    }
    __syncthreads();
    if (t < 16) {
      float s = 0.f, s2 = 0.f;
#pragma unroll
      for (int w = 0; w < 4; w++) { s += Pred[t * 8 + w * 2]; s2 += Pred[t * 8 + w * 2 + 1]; }
      float mean = s * (1.0f / 512.0f);
      float var  = s2 * (1.0f / 512.0f) - mean * mean;
      MV[t * 2]     = mean;
      MV[t * 2 + 1] = rsqrtf(var + 1e-5f);
    }
    __syncthreads();
    float lww[8], lbb_[8];
#pragma unroll
    for (int ni = 0; ni < 8; ni++) {
      lww[ni]  = lw[n0w + ni * 16 + lm];
      lbb_[ni] = lb[n0w + ni * 16 + lm];
    }
#pragma unroll
    for (int r = 0; r < 4; r++) {
      int row = quad * 4 + r;
      float mean = MV[row * 2], rstd = MV[row * 2 + 1];
      size_t obase = (size_t)(m0 + row) * 512 + n0w;
#pragma unroll
      for (int ni = 0; ni < 8; ni++)
        out[obase + ni * 16 + lm] =
            __float2bfloat16((acc[ni][r] - mean) * rstd * lww[ni] + lbb_[ni]);
    }
  } else {
    bf16* As = (bf16*)sm;
    bf16* Bs = (bf16*)(sm + 18432);
    const bf16* A    = (z == 3) ? fb : fa;
    const bf16* Wt   = (z == 3) ? Wvt : Wgt;
    const float* bias = (z == 3) ? bv : bg;
    int x = blockIdx.x;
    int m0 = (x >> 3) * 128, n0 = (x & 7) * 64;
    int wm = wave * 32;
    f32x4 acc[2][4] = {};
    for (int k0 = 0; k0 < 256; k0 += 64) {
      __syncthreads();
#pragma unroll
      for (int i = 0; i < 4; i++) {
        int id = t + 256 * i, r = id >> 3, cg = id & 7;
        *(ushort8_t*)(&As[r * 72 + cg * 8]) =
            *(const ushort8_t*)(A + (size_t)(m0 + r) * 256 + k0 + cg * 8);
      }
#pragma unroll
      for (int i = 0; i < 2; i++) {
        int id = t + 256 * i, r = id >> 3, cg = id & 7;
        *(ushort8_t*)(&Bs[r * 72 + cg * 8]) =
            *(const ushort8_t*)(Wt + (size_t)(n0 + r) * 256 + k0 + cg * 8);
      }
      __syncthreads();
#pragma unroll
      for (int kk = 0; kk < 64; kk += 32) {
        bf16x8 af[2], bf_[4];
#pragma unroll
        for (int mi = 0; mi < 2; mi++)
          af[mi] = *(const bf16x8*)(&As[(wm + mi * 16 + lm) * 72 + kk + q8]);
#pragma unroll
        for (int ni = 0; ni < 4; ni++)
          bf_[ni] = *(const bf16x8*)(&Bs[(ni * 16 + lm) * 72 + kk + q8]);
#pragma unroll
        for (int mi = 0; mi < 2; mi++)
#pragma unroll
          for (int ni = 0; ni < 4; ni++)
            acc[mi][ni] = MFMA32(af[mi], bf_[ni], acc[mi][ni]);
      }
    }
    if (z == 2) {
#pragma unroll
      for (int mi = 0; mi < 2; mi++)
#pragma unroll
        for (int ni = 0; ni < 4; ni++) {
          int nn = n0 + ni * 16 + lm;
          float bvv = bias[nn];
          int mb = m0 + wm + mi * 16 + quad * 4;
#pragma unroll
          for (int r = 0; r < 4; r++)
            gout[(size_t)(mb + r) * 512 + nn] = __float2bfloat16(acc[mi][ni][r] + bvv);
        }
    } else {
      __syncthreads();
      bf16* buf = (bf16*)sm;
#pragma unroll
      for (int mi = 0; mi < 2; mi++)
#pragma unroll
        for (int ni = 0; ni < 4; ni++) {
          int d_local = ni * 16 + lm;
          float bvv = bias[n0 + d_local];
          int j_local = wm + mi * 16 + quad * 4;
#pragma unroll
          for (int r = 0; r < 4; r++)
            buf[d_local * 136 + j_local + r] = __float2bfloat16(acc[mi][ni][r] + bvv);
        }
      __syncthreads();
      int bidx2 = m0 >> 11, j0g = m0 & 2047, hh = n0 >> 6;
      int dl = t >> 2, jseg = (t & 3) * 32;
      bf16* dstrow = vout + (size_t)((bidx2 * 8 + hh) * 64 + dl) * 2048 + j0g + jseg;
#pragma unroll
      for (int c = 0; c < 4; c++)
        *(ushort8_t*)(dstrow + c * 8) = *(const ushort8_t*)(&buf[dl * 136 + jseg + c * 8]);
    }
  }
}

// ---------------- flash attention, 32x32x16 MFMA, register-resident P ----------
// 8 waves = (ig in {0,1}: i-half of 32 q-rows) x (js in 0..3: j-quarter of 32).
// j-tile 128/iter staged once for all waves. St = K.Q^T via 32x32x16:
// C col = i = lane&31, row = j = (reg&3)+8*(reg>>2)+4*(lane>>5)  [m74/m101].
// P converted in-register to PV B-operand (k=8*(lane>>5)+idx) with shfl_xor(32).
// PV: O^T[d][i] += V^T-frag (A) x P (B). 4-way js merge + LDS transpose epilogue.
__global__ __launch_bounds__(512, 4) void attn_kernel(
    const bf16* __restrict__ q, const bf16* __restrict__ k,
    const bf16* __restrict__ vt, const bf16* __restrict__ g,
    const u64* __restrict__ mbits,
    bf16* __restrict__ gh, bf16* __restrict__ gl) {
  __shared__ __align__(16) char smem[46080];
  bf16* Ks = (bf16*)smem;                 // [128][72] = 18432 B
  bf16* Vs = (bf16*)(smem + 18432);       // [64][136] = 17408 B
  bf16* Qs = (bf16*)(smem + 35840);       // [64][72]  = 9216 B (pre-loop only)
  float* Lbuf = (float*)(smem + 45056);   // 4 js x 64 rows = 1024 B
  float* OmA = (float*)smem;              // post-loop: 4 bufs of [64][33] f32 (33792 B)
  bf16* Tbuf = (bf16*)(smem + 35840);     // post-loop: [64][72] bf16 (overlay Qs)

  int qt = blockIdx.x, bh = blockIdx.y;
  int bidx = bh >> 3, hh = bh & 7;
  int i0 = qt * 64;
  int t = threadIdx.x, w = t >> 6, lane = t & 63;
  int ig = w & 1, js = w >> 1;
  int l31 = lane & 31, hf = lane >> 5;

  // stage Q (64 x 64), one b128 per thread
  {
    int r = t >> 3, cg = t & 7;
    *(ushort8_t*)(&Qs[r * 72 + cg * 8]) =
        *(const ushort8_t*)(q + (size_t)(bidx * NA_ + i0 + r) * INNER_ + hh * DH_ + cg * 8);
  }
  __syncthreads();
  // Q B-frags: B[n=i=l31][k=16kt+8hf+idx]
  bf16x8 bq[4];
#pragma unroll
  for (int kt = 0; kt < 4; kt++)
    bq[kt] = *(const bf16x8*)(&Qs[(ig * 32 + l31) * 72 + kt * 16 + hf * 8]);

  f32x16 oT[2];
#pragma unroll
  for (int i = 0; i < 16; i++) { oT[0][i] = 0.f; oT[1][i] = 0.f; }
  float psum = 0.f;
  const float scale2 = 0.125f * 1.44269504088896f;

  const bf16* kb = k + (size_t)(bidx * NB_) * INNER_ + hh * DH_;
  const bf16* vb = vt + (size_t)(bh * DH_) * NB_;
  const u64* mrp = mbits + (size_t)(bidx * NA_ + i0 + ig * 32 + l31) * (NB_ / 64);
  int msh = (js & 1) * 32 + hf * 4;

  for (int it = 0; it < 16; it++) {
    int j0 = it * 128;
    __syncthreads();
#pragma unroll
    for (int i = 0; i < 2; i++) {
      int id = t + 512 * i;
      {
        int r = id >> 3, cg = id & 7;  // K: 128 j-rows x 64 dh
        *(ushort8_t*)(&Ks[r * 72 + cg * 8]) =
            *(const ushort8_t*)(kb + (size_t)(j0 + r) * INNER_ + cg * 8);
      }
      {
        int d = id >> 4, jg = id & 15;  // V^T: 64 d x 128 j
        *(ushort8_t*)(&Vs[d * 136 + jg * 8]) =
            *(const ushort8_t*)(vb + (size_t)d * NB_ + j0 + jg * 8);
      }
    }
    u64 wm_ = mrp[it * 2 + (js >> 1)];
    __syncthreads();

    // St = K.Q^T  (m=j 32 rows of this js-quarter, n=i 32 rows of this ig-half)
    f32x16 st;
#pragma unroll
    for (int i = 0; i < 16; i++) st[i] = 0.f;
#pragma unroll
    for (int kt = 0; kt < 4; kt++) {
      bf16x8 ka = *(const bf16x8*)(&Ks[(js * 32 + l31) * 72 + kt * 16 + hf * 8]);
      st = MFMA3216(ka, bq[kt], st);
    }

    // softmax numerator + mask + pack (j = (reg&3)+8*(reg>>2)+4*hf within quarter)
    unsigned mlo = (unsigned)(wm_ >> msh);
    float pr[16];
#pragma unroll
    for (int reg = 0; reg < 16; reg++) {
      float p = exp2f(st[reg] * scale2);
      unsigned bitpos = (unsigned)((reg & 3) + 8 * (reg >> 2));
      pr[reg] = ((mlo >> bitpos) & 1u) ? p : 0.f;
    }
#pragma unroll
    for (int i = 0; i < 16; i += 4)
      psum += ((pr[i] + pr[i + 1]) + (pr[i + 2] + pr[i + 3]));
    unsigned dw[8];
#pragma unroll
    for (int p = 0; p < 8; p++)
      dw[p] = (unsigned)bfbits(pr[2 * p]) | ((unsigned)bfbits(pr[2 * p + 1]) << 16);

    // in-register transpose to PV B-frag layout via lane^32 exchange
    unsigned rx[8];
#pragma unroll
    for (int p = 0; p < 8; p++) rx[p] = (unsigned)__shfl_xor((int)dw[p], 32);
    unsigned f0[4], f1[4];
    if (hf == 0) {
      f0[0] = dw[0]; f0[1] = dw[1]; f0[2] = rx[0]; f0[3] = rx[1];
      f1[0] = dw[4]; f1[1] = dw[5]; f1[2] = rx[4]; f1[3] = rx[5];
    } else {
      f0[0] = rx[2]; f0[1] = rx[3]; f0[2] = dw[2]; f0[3] = dw[3];
      f1[0] = rx[6]; f1[1] = rx[7]; f1[2] = dw[6]; f1[3] = dw[7];
    }
    bf16x8 pf0 = __builtin_bit_cast(bf16x8, *(uint4*)f0);
    bf16x8 pf1 = __builtin_bit_cast(bf16x8, *(uint4*)f1);

    // PV: O^T[m=d][n=i] += V^T-frag . P-frag
#pragma unroll
    for (int dt = 0; dt < 2; dt++) {
      bf16x8 va0 = *(const bf16x8*)(&Vs[(dt * 32 + l31) * 136 + js * 32 + hf * 8]);
      bf16x8 va1 = *(const bf16x8*)(&Vs[(dt * 32 + l31) * 136 + js * 32 + 16 + hf * 8]);
      oT[dt] = MFMA3216(va0, pf0, oT[dt]);
      oT[dt] = MFMA3216(va1, pf1, oT[dt]);
    }
  }

  // full row-sum per i (combine lane halves)
  psum += __shfl_xor(psum, 32);

  // ---------------- 4-way js merge of O^T and psum ----------------
  __syncthreads();
  if (lane < 32) Lbuf[js * 64 + ig * 32 + l31] = psum;
  if (js & 1) {
    float* B = OmA + (size_t)(ig * 2 + (js >> 1)) * 2112;
#pragma unroll
    for (int dt = 0; dt < 2; dt++)
#pragma unroll
      for (int reg = 0; reg < 16; reg++) {
        int d = dt * 32 + (reg & 3) + 8 * (reg >> 2) + 4 * hf;
        B[d * 33 + l31] = oT[dt][reg];
      }
  }
  __syncthreads();
  if (!(js & 1)) {
    float* B = OmA + (size_t)(ig * 2 + (js >> 1)) * 2112;
#pragma unroll
    for (int dt = 0; dt < 2; dt++)
#pragma unroll
      for (int reg = 0; reg < 16; reg++) {
        int d = dt * 32 + (reg & 3) + 8 * (reg >> 2) + 4 * hf;
        oT[dt][reg] += B[d * 33 + l31];
      }
  }
  __syncthreads();
  if (js == 2) {
    float* B = OmA + (size_t)(ig * 2 + 1) * 2112;
#pragma unroll
    for (int dt = 0; dt < 2; dt++)
#pragma unroll
      for (int reg = 0; reg < 16; reg++) {
        int d = dt * 32 + (reg & 3) + 8 * (reg >> 2) + 4 * hf;
        B[d * 33 + l31] = oT[dt][reg];
      }
  }
  __syncthreads();
  if (js == 0) {
    float* B = OmA + (size_t)(ig * 2 + 1) * 2112;
#pragma unroll
    for (int dt = 0; dt < 2; dt++)
#pragma unroll
      for (int reg = 0; reg < 16; reg++) {
        int d = dt * 32 + (reg & 3) + 8 * (reg >> 2) + 4 * hf;
        oT[dt][reg] += B[d * 33 + l31];
      }
    int il = ig * 32 + l31;
    float l = ((Lbuf[il] + Lbuf[64 + il]) + (Lbuf[128 + il] + Lbuf[192 + il]));
    float inv = 1.0f / l;
    // gate: g row fixed per lane
    size_t gpb = (size_t)(bidx * NA_ + i0 + il) * INNER_ + hh * DH_;
#pragma unroll
    for (int dt = 0; dt < 2; dt++)
#pragma unroll
      for (int rg = 0; rg < 4; rg++) {
        int dbase = dt * 32 + rg * 8 + hf * 4;
        short4 g4 = *(const short4*)(g + gpb + dbase);
        unsigned short gu[4] = {(unsigned short)g4.x, (unsigned short)g4.y,
                                (unsigned short)g4.z, (unsigned short)g4.w};
#pragma unroll
        for (int rr = 0; rr < 4; rr++) {
          float gvf = b2f(gu[rr]);
          float sig = 1.0f / (1.0f + __expf(-gvf));
          oT[dt][rg * 4 + rr] = oT[dt][rg * 4 + rr] * inv * sig;
        }
      }
  }
  // ---- transposed coalesced store: pass 1 (hi), pass 2 (lo) ----
  __syncthreads();
  if (js == 0) {
    int il = ig * 32 + l31;
#pragma unroll
    for (int dt = 0; dt < 2; dt++)
#pragma unroll
      for (int rg = 0; rg < 4; rg++) {
        int dbase = dt * 32 + rg * 8 + hf * 4;
        unsigned w0 = (unsigned)bfbits(oT[dt][rg * 4 + 0]) |
                      ((unsigned)bfbits(oT[dt][rg * 4 + 1]) << 16);
        unsigned w1 = (unsigned)bfbits(oT[dt][rg * 4 + 2]) |
                      ((unsigned)bfbits(oT[dt][rg * 4 + 3]) << 16);
        *(unsigned*)(&Tbuf[il * 72 + dbase])     = w0;
        *(unsigned*)(&Tbuf[il * 72 + dbase + 2]) = w1;
      }
  }
  __syncthreads();
  {
    int ri = t >> 3, seg = t & 7;
    ushort8_t v = *(const ushort8_t*)(&Tbuf[ri * 72 + seg * 8]);
    *(ushort8_t*)(gh + (size_t)(bidx * NA_ + i0 + ri) * INNER_ + hh * DH_ + seg * 8) = v;
  }
  __syncthreads();
  if (js == 0) {
    int il = ig * 32 + l31;
#pragma unroll
    for (int dt = 0; dt < 2; dt++)
#pragma unroll
      for (int rg = 0; rg < 4; rg++) {
        int dbase = dt * 32 + rg * 8 + hf * 4;
        unsigned short lo[4];
#pragma unroll
        for (int rr = 0; rr < 4; rr++) {
          float v = oT[dt][rg * 4 + rr];
          lo[rr] = bfbits(v - b2f(bfbits(v)));
        }
        *(unsigned*)(&Tbuf[il * 72 + dbase])     = (unsigned)lo[0] | ((unsigned)lo[1] << 16);
        *(unsigned*)(&Tbuf[il * 72 + dbase + 2]) = (unsigned)lo[2] | ((unsigned)lo[3] << 16);
      }
  }
  __syncthreads();
  {
    int ri = t >> 3, seg = t & 7;
    ushort8_t v = *(const ushort8_t*)(&Tbuf[ri * 72 + seg * 8]);
    *(ushort8_t*)(gl + (size_t)(bidx * NA_ + i0 + ri) * INNER_ + hh * DH_ + seg * 8) = v;
  }
}

// ---------------- final GEMM in split-bf16 (hi/lo), 32x64 tiles, fp32 out -------
__global__ __launch_bounds__(256) void gemm_split_kernel(
    const bf16* __restrict__ Ah, const bf16* __restrict__ Al,
    const bf16* __restrict__ Bh, const bf16* __restrict__ Bl,
    const float* __restrict__ bias, float* __restrict__ C) {
  constexpr int K = 512, N = 256;
  __shared__ __align__(16) bf16 Ash[32 * 72];
  __shared__ __align__(16) bf16 Asl[32 * 72];
  __shared__ __align__(16) bf16 Bsh[64 * 72];
  __shared__ __align__(16) bf16 Bsl[64 * 72];
  int n0 = blockIdx.x * 64, m0 = blockIdx.y * 32;
  int t = threadIdx.x, wave = t >> 6, lane = t & 63;
  int lm = lane & 15, quad = lane >> 4, q8 = quad * 8;
  int wm = (wave & 1) * 16, wn = (wave >> 1) * 32;
  f32x4 acc[2] = {};
  for (int k0 = 0; k0 < K; k0 += 64) {
    __syncthreads();
    {
      int r = t >> 3, cg = t & 7;
      size_t ga = (size_t)(m0 + r) * K + k0 + cg * 8;
      *(ushort8_t*)(&Ash[r * 72 + cg * 8]) = *(const ushort8_t*)(Ah + ga);
      *(ushort8_t*)(&Asl[r * 72 + cg * 8]) = *(const ushort8_t*)(Al + ga);
    }
#pragma unroll
    for (int i = 0; i < 2; i++) {
      int id = t + 256 * i, r = id >> 3, cg = id & 7;
      size_t gb = (size_t)(n0 + r) * K + k0 + cg * 8;
      *(ushort8_t*)(&Bsh[r * 72 + cg * 8]) = *(const ushort8_t*)(Bh + gb);
      *(ushort8_t*)(&Bsl[r * 72 + cg * 8]) = *(const ushort8_t*)(Bl + gb);
    }
    __syncthreads();
#pragma unroll
    for (int kk = 0; kk < 64; kk += 32) {
      bf16x8 ah = *(const bf16x8*)(&Ash[(wm + lm) * 72 + kk + q8]);
      bf16x8 al = *(const bf16x8*)(&Asl[(wm + lm) * 72 + kk + q8]);
#pragma unroll
      for (int ni = 0; ni < 2; ni++) {
        bf16x8 bh_ = *(const bf16x8*)(&Bsh[(wn + ni * 16 + lm) * 72 + kk + q8]);
        bf16x8 bl_ = *(const bf16x8*)(&Bsl[(wn + ni * 16 + lm) * 72 + kk + q8]);
        acc[ni] = MFMA32(ah, bh_, acc[ni]);
        acc[ni] = MFMA32(ah, bl_, acc[ni]);
        acc[ni] = MFMA32(al, bh_, acc[ni]);
      }
    }
  }
#pragma unroll
  for (int ni = 0; ni < 2; ni++) {
    int n = n0 + wn + ni * 16 + lm;
    float bvv = bias[n];
    int mb = m0 + wm + quad * 4;
#pragma unroll
    for (int r = 0; r < 4; r++) C[(size_t)(mb + r) * N + n] = acc[ni][r] + bvv;
  }
}

extern "C" void kernel_launch(void* const* d_in, const int* in_sizes, int n_in,
                              void* d_out, int out_size, void* d_ws, size_t ws_size,
                              hipStream_t stream) {
  const float* feat_a = (const float*)d_in[0];
  const float* feat_b = (const float*)d_in[1];
  const void*  mask   = d_in[2];
  const float* Wq = (const float*)d_in[3];
  const float* bq = (const float*)d_in[4];
  const float* Wk = (const float*)d_in[5];
  const float* bk = (const float*)d_in[6];
  const float* Wv = (const float*)d_in[7];
  const float* bv = (const float*)d_in[8];
  const float* Wg = (const float*)d_in[9];
  const float* bg = (const float*)d_in[10];
  const float* Wo = (const float*)d_in[11];
  const float* bo = (const float*)d_in[12];
  const float* law = (const float*)d_in[13];
  const float* lab = (const float*)d_in[14];
  const float* lbw = (const float*)d_in[15];
  const float* lbb = (const float*)d_in[16];
  const float* qlw = (const float*)d_in[17];
  const float* qlb = (const float*)d_in[18];
  const float* klw = (const float*)d_in[19];
  const float* klb = (const float*)d_in[20];

  char* ws = (char*)d_ws;
  size_t off = 0;
  auto alloc = [&](size_t bytes) -> void* {
    void* p = ws + off;
    off += (bytes + 255) & ~(size_t)255;
    return p;
  };
  bf16* fa    = (bf16*)alloc((size_t)MROWS * 256 * 2);
  bf16* fb    = (bf16*)alloc((size_t)MROWS * 256 * 2);
  bf16* Wqt   = (bf16*)alloc((size_t)131072 * 2);
  bf16* Wkt   = (bf16*)alloc((size_t)131072 * 2);
  bf16* Wvt   = (bf16*)alloc((size_t)131072 * 2);
  bf16* Wgt   = (bf16*)alloc((size_t)131072 * 2);
  bf16* Woth  = (bf16*)alloc((size_t)131072 * 2);
  bf16* Wotl  = (bf16*)alloc((size_t)131072 * 2);
  bf16* qb_   = (bf16*)alloc((size_t)MROWS * 512 * 2);
  bf16* kb_   = (bf16*)alloc((size_t)MROWS * 512 * 2);
  bf16* vtb   = (bf16*)alloc((size_t)1024 * 2048 * 2);
  bf16* gbuf  = (bf16*)alloc((size_t)MROWS * 512 * 2);
  bf16* gh    = (bf16*)alloc((size_t)MROWS * 512 * 2);
  bf16* gl    = (bf16*)alloc((size_t)MROWS * 512 * 2);
  u64*  mbits = (u64*)alloc((size_t)131072 * 8);

  prep_kernel<<<6656, 256, 0, stream>>>(
      feat_a, feat_b, law, lab, lbw, lbb, fa, fb,
      Wq, Wk, Wv, Wg, Wo, Wqt, Wkt, Wvt, Wgt, Woth, Wotl, mask, mbits);
  gemm4_kernel<<<dim3(256, 1, 4), 256, 0, stream>>>(
      fa, fb, Wqt, Wkt, Wgt, Wvt, bq, bk, bg, bv,
      qlw, qlb, klw, klb, qb_, kb_, gbuf, vtb);
  attn_kernel<<<dim3(32, 16), 512, 0, stream>>>(qb_, kb_, vtb, gbuf, mbits, gh, gl);
  gemm_split_kernel<<<dim3(4, 128), 256, 0, stream>>>(gh, gl, Woth, Wotl, bo, (float*)d_out);
}